// Round 1
// baseline (2121.469 us; speedup 1.0000x reference)
//
#include <hip/hip_runtime.h>

#define B_ 4
#define S_ 4096
#define D_ 1024

typedef __bf16 bf16;
typedef __attribute__((ext_vector_type(8))) __bf16 bf16x8;
typedef __attribute__((ext_vector_type(4))) float floatx4;

__device__ inline floatx4 mfma16(bf16x8 a, bf16x8 b, floatx4 c) {
    return __builtin_amdgcn_mfma_f32_16x16x32_bf16(a, b, c, 0, 0, 0);
}

__device__ inline bf16x8 cvt8(float4 a, float4 b) {
    bf16x8 h;
    h[0] = (bf16)a.x; h[1] = (bf16)a.y; h[2] = (bf16)a.z; h[3] = (bf16)a.w;
    h[4] = (bf16)b.x; h[5] = (bf16)b.y; h[6] = (bf16)b.z; h[7] = (bf16)b.w;
    return h;
}

// C[m][n] = (sum_k A[m][k]*W[n][k] + bias1[n] + bias2[n]) * scale, output bf16.
// A: [16384][1024] fp32, W: [1024][1024] fp32. Tile 64x64, BK=32, 4 waves.
#define SSTR 40  // LDS row stride (bf16): 16B-aligned rows, 2-way banks only
__global__ __launch_bounds__(256) void proj_gemm(
    const float* __restrict__ A, const float* __restrict__ W,
    const float* __restrict__ bias1, const float* __restrict__ bias2,
    bf16* __restrict__ C, float scale)
{
    __shared__ bf16 sA[64 * SSTR];
    __shared__ bf16 sB[64 * SSTR];
    const int tid = threadIdx.x;
    const int wave = tid >> 6, lane = tid & 63, quad = lane >> 4, l16 = lane & 15;
    const int m0 = blockIdx.x * 64, n0 = blockIdx.y * 64;
    const int wr = (wave >> 1) * 32, wc = (wave & 1) * 32;
    const int lr = tid >> 2;          // staging row 0..63
    const int lc = (tid & 3) * 8;     // staging col 0,8,16,24

    floatx4 acc[2][2];
#pragma unroll
    for (int i = 0; i < 2; i++)
#pragma unroll
        for (int j = 0; j < 2; j++) acc[i][j] = (floatx4)0.0f;

    for (int k0 = 0; k0 < 1024; k0 += 32) {
        const float* ga = A + (m0 + lr) * 1024 + k0 + lc;
        const float* gw = W + (n0 + lr) * 1024 + k0 + lc;
        float4 a0 = *(const float4*)ga;
        float4 a1 = *(const float4*)(ga + 4);
        float4 w0 = *(const float4*)gw;
        float4 w1 = *(const float4*)(gw + 4);
        *(bf16x8*)&sA[lr * SSTR + lc] = cvt8(a0, a1);
        *(bf16x8*)&sB[lr * SSTR + lc] = cvt8(w0, w1);
        __syncthreads();
        bf16x8 af[2], bfv[2];
        af[0]  = *(bf16x8*)&sA[(wr + l16) * SSTR + quad * 8];
        af[1]  = *(bf16x8*)&sA[(wr + 16 + l16) * SSTR + quad * 8];
        bfv[0] = *(bf16x8*)&sB[(wc + l16) * SSTR + quad * 8];
        bfv[1] = *(bf16x8*)&sB[(wc + 16 + l16) * SSTR + quad * 8];
#pragma unroll
        for (int mf = 0; mf < 2; mf++)
#pragma unroll
            for (int nf = 0; nf < 2; nf++)
                acc[mf][nf] = mfma16(af[mf], bfv[nf], acc[mf][nf]);
        __syncthreads();
    }
#pragma unroll
    for (int mf = 0; mf < 2; mf++)
#pragma unroll
        for (int nf = 0; nf < 2; nf++) {
            int col = n0 + wc + nf * 16 + l16;
            float bsum = bias1[col] + (bias2 ? bias2[col] : 0.0f);
#pragma unroll
            for (int r = 0; r < 4; r++) {
                int row = m0 + wr + mf * 16 + quad * 4 + r;
                C[row * 1024 + col] = (bf16)((acc[mf][nf][r] + bsum) * scale);
            }
        }
}

// vb [b][s][d] -> vtb [b][d][s]
__global__ __launch_bounds__(256) void transpose_v(
    const bf16* __restrict__ vb, bf16* __restrict__ vtb)
{
    __shared__ bf16 tile[32][33];
    const int b = blockIdx.z;
    const int s0 = blockIdx.x * 32, d0 = blockIdx.y * 32;
    const int tr = threadIdx.x >> 5;   // 0..7
    const int tc = threadIdx.x & 31;
#pragma unroll
    for (int k = 0; k < 4; k++) {
        int r = tr + k * 8;
        tile[r][tc] = vb[(b * S_ + s0 + r) * D_ + d0 + tc];
    }
    __syncthreads();
#pragma unroll
    for (int k = 0; k < 4; k++) {
        int r = tr + k * 8;
        vtb[(b * D_ + d0 + r) * S_ + s0 + tc] = tile[tc][r];
    }
}

// Flash attention: scores = qb . vb^T (scale prefolded into qb), online softmax,
// O = P . V. One block = (batch, 32 q-rows). 4 waves split D into 256-chunks.
#define BR 32
#define TK 64
#define DC 256
__global__ __launch_bounds__(256, 2) void flash_attn(
    const bf16* __restrict__ qb, const bf16* __restrict__ vb,
    const bf16* __restrict__ vtb, float* __restrict__ out)
{
    __shared__ float sPart[4][32][65];
    __shared__ bf16 sP[32][72];
    __shared__ float sM[32], sL[32], sAlpha[32];

    const int tid = threadIdx.x;
    const int wave = tid >> 6, lane = tid & 63, quad = lane >> 4, l16 = lane & 15;
    const int b = blockIdx.y, q0 = blockIdx.x * BR;

    // Resident Q fragments: A[m=l16][k=quad*8+j], rows q0+mf*16+l16, wave's d-chunk
    bf16x8 qf[2][8];
#pragma unroll
    for (int mf = 0; mf < 2; mf++)
#pragma unroll
        for (int ks = 0; ks < 8; ks++) {
            int row = q0 + mf * 16 + l16;
            int col = wave * DC + ks * 32 + quad * 8;
            qf[mf][ks] = *(const bf16x8*)(qb + (b * S_ + row) * D_ + col);
        }

    floatx4 o[2][16];
#pragma unroll
    for (int mf = 0; mf < 2; mf++)
#pragma unroll
        for (int nf = 0; nf < 16; nf++) o[mf][nf] = (floatx4)0.0f;

    if (tid < 32) { sM[tid] = -1e30f; sL[tid] = 0.0f; }
    __syncthreads();

    for (int kt = 0; kt < S_ / TK; kt++) {
        const int k0 = kt * TK;
        // ---- partial scores over this wave's 256-wide d chunk ----
        floatx4 sp[2][4];
#pragma unroll
        for (int mf = 0; mf < 2; mf++)
#pragma unroll
            for (int nf = 0; nf < 4; nf++) sp[mf][nf] = (floatx4)0.0f;
#pragma unroll
        for (int ks = 0; ks < 8; ks++) {
            int col = wave * DC + ks * 32 + quad * 8;
#pragma unroll
            for (int nf = 0; nf < 4; nf++) {
                int key = k0 + nf * 16 + l16;
                bf16x8 vf = *(const bf16x8*)(vb + (b * S_ + key) * D_ + col);
                sp[0][nf] = mfma16(qf[0][ks], vf, sp[0][nf]);
                sp[1][nf] = mfma16(qf[1][ks], vf, sp[1][nf]);
            }
        }
#pragma unroll
        for (int mf = 0; mf < 2; mf++)
#pragma unroll
            for (int nf = 0; nf < 4; nf++)
#pragma unroll
                for (int r = 0; r < 4; r++)
                    sPart[wave][mf * 16 + quad * 4 + r][nf * 16 + l16] = sp[mf][nf][r];
        __syncthreads();

        // ---- reduce partials + online softmax (8 threads per row) ----
        {
            const int rr = tid >> 3, c0 = (tid & 7) * 8;
            float v[8];
            float mx = -1e30f;
#pragma unroll
            for (int j = 0; j < 8; j++) {
                v[j] = sPart[0][rr][c0 + j] + sPart[1][rr][c0 + j] +
                       sPart[2][rr][c0 + j] + sPart[3][rr][c0 + j];
                mx = fmaxf(mx, v[j]);
            }
            mx = fmaxf(mx, __shfl_xor(mx, 1));
            mx = fmaxf(mx, __shfl_xor(mx, 2));
            mx = fmaxf(mx, __shfl_xor(mx, 4));
            float m_old = sM[rr];
            float m_new = fmaxf(m_old, mx);
            float rsum = 0.0f;
#pragma unroll
            for (int j = 0; j < 8; j++) {
                float p = __expf(v[j] - m_new);
                sP[rr][c0 + j] = (bf16)p;
                rsum += p;
            }
            rsum += __shfl_xor(rsum, 1);
            rsum += __shfl_xor(rsum, 2);
            rsum += __shfl_xor(rsum, 4);
            if ((tid & 7) == 0) {
                float alpha = __expf(m_old - m_new);
                sAlpha[rr] = alpha;
                sM[rr] = m_new;
                sL[rr] = sL[rr] * alpha + rsum;
            }
        }
        __syncthreads();

        // ---- rescale O, then PV ----
        float al[2][4];
#pragma unroll
        for (int mf = 0; mf < 2; mf++)
#pragma unroll
            for (int r = 0; r < 4; r++) al[mf][r] = sAlpha[mf * 16 + quad * 4 + r];
#pragma unroll
        for (int mf = 0; mf < 2; mf++)
#pragma unroll
            for (int nf = 0; nf < 16; nf++)
#pragma unroll
                for (int r = 0; r < 4; r++) o[mf][nf][r] *= al[mf][r];

#pragma unroll
        for (int ks2 = 0; ks2 < 2; ks2++) {
            bf16x8 pA[2];
            pA[0] = *(bf16x8*)&sP[l16][ks2 * 32 + quad * 8];
            pA[1] = *(bf16x8*)&sP[16 + l16][ks2 * 32 + quad * 8];
            int key = k0 + ks2 * 32 + quad * 8;
#pragma unroll
            for (int nf = 0; nf < 16; nf++) {
                int d = wave * DC + nf * 16 + l16;
                bf16x8 vtf = *(const bf16x8*)(vtb + (b * D_ + d) * S_ + key);
                o[0][nf] = mfma16(pA[0], vtf, o[0][nf]);
                o[1][nf] = mfma16(pA[1], vtf, o[1][nf]);
            }
        }
        __syncthreads();
    }

    // ---- epilogue: O / l ----
#pragma unroll
    for (int mf = 0; mf < 2; mf++) {
        float inv[4];
#pragma unroll
        for (int r = 0; r < 4; r++) inv[r] = 1.0f / sL[mf * 16 + quad * 4 + r];
#pragma unroll
        for (int nf = 0; nf < 16; nf++) {
            int d = wave * DC + nf * 16 + l16;
#pragma unroll
            for (int r = 0; r < 4; r++) {
                int row = q0 + mf * 16 + quad * 4 + r;
                out[(b * S_ + row) * D_ + d] = o[mf][nf][r] * inv[r];
            }
        }
    }
}

extern "C" void kernel_launch(void* const* d_in, const int* in_sizes, int n_in,
                              void* d_out, int out_size, void* d_ws, size_t ws_size,
                              hipStream_t stream) {
    const float* query = (const float*)d_in[0];
    const float* value = (const float*)d_in[1];
    const float* Wq    = (const float*)d_in[2];
    const float* bq    = (const float*)d_in[3];
    const float* qk_b  = (const float*)d_in[4];
    const float* Wv    = (const float*)d_in[5];
    const float* bv    = (const float*)d_in[6];
    float* out = (float*)d_out;

    bf16* qb  = (bf16*)d_ws;                 // [4][4096][1024] bf16, scale+bias folded
    bf16* vb  = qb + (size_t)B_ * S_ * D_;   // [4][4096][1024] bf16
    bf16* vtb = vb + (size_t)B_ * S_ * D_;   // [4][1024][4096] bf16

    dim3 pg(16384 / 64, 1024 / 64);
    // qb = (query . Wq^T + bq + qk_b) / 8
    proj_gemm<<<pg, 256, 0, stream>>>(query, Wq, bq, qk_b, qb, 0.125f);
    // vb = value . Wv^T + bv
    proj_gemm<<<pg, 256, 0, stream>>>(value, Wv, bv, nullptr, vb, 1.0f);
    transpose_v<<<dim3(S_ / 32, D_ / 32, B_), 256, 0, stream>>>(vb, vtb);
    flash_attn<<<dim3(S_ / BR, B_), 256, 0, stream>>>(qb, vb, vtb, out);
}

// Round 2
// 1112.045 us; speedup vs baseline: 1.9077x; 1.9077x over previous
//
#include <hip/hip_runtime.h>

#define B_ 4
#define S_ 4096
#define D_ 1024

typedef __bf16 bf16;
typedef _Float16 f16;
typedef __attribute__((ext_vector_type(8))) __bf16 bf16x8;
typedef __attribute__((ext_vector_type(8))) _Float16 f16x8;
typedef __attribute__((ext_vector_type(4))) float floatx4;

__device__ inline floatx4 mfma16(bf16x8 a, bf16x8 b, floatx4 c) {
    return __builtin_amdgcn_mfma_f32_16x16x32_bf16(a, b, c, 0, 0, 0);
}
__device__ inline floatx4 mfma_any(bf16x8 a, bf16x8 b, floatx4 c) {
    return __builtin_amdgcn_mfma_f32_16x16x32_bf16(a, b, c, 0, 0, 0);
}
__device__ inline floatx4 mfma_any(f16x8 a, f16x8 b, floatx4 c) {
    return __builtin_amdgcn_mfma_f32_16x16x32_f16(a, b, c, 0, 0, 0);
}

template <typename T> struct vec8_of;
template <> struct vec8_of<bf16> { using type = bf16x8; };
template <> struct vec8_of<f16>  { using type = f16x8; };

__device__ inline bf16x8 cvt8(float4 a, float4 b) {
    bf16x8 h;
    h[0] = (bf16)a.x; h[1] = (bf16)a.y; h[2] = (bf16)a.z; h[3] = (bf16)a.w;
    h[4] = (bf16)b.x; h[5] = (bf16)b.y; h[6] = (bf16)b.z; h[7] = (bf16)b.w;
    return h;
}

// ---------------------------------------------------------------------------
// proj: C[m][n] = (sum_k A[m][k]*W[n][k] + bias1[n] + bias2[n]) * scale (bf16)
// ---------------------------------------------------------------------------
#define SSTR 40
__global__ __launch_bounds__(256) void proj_gemm(
    const float* __restrict__ A, const float* __restrict__ W,
    const float* __restrict__ bias1, const float* __restrict__ bias2,
    bf16* __restrict__ C, float scale)
{
    __shared__ bf16 sA[64 * SSTR];
    __shared__ bf16 sB[64 * SSTR];
    const int tid = threadIdx.x;
    const int wave = tid >> 6, lane = tid & 63, quad = lane >> 4, l16 = lane & 15;
    const int m0 = blockIdx.x * 64, n0 = blockIdx.y * 64;
    const int wr = (wave >> 1) * 32, wc = (wave & 1) * 32;
    const int lr = tid >> 2;
    const int lc = (tid & 3) * 8;

    floatx4 acc[2][2];
#pragma unroll
    for (int i = 0; i < 2; i++)
#pragma unroll
        for (int j = 0; j < 2; j++) acc[i][j] = (floatx4)0.0f;

    for (int k0 = 0; k0 < 1024; k0 += 32) {
        const float* ga = A + (size_t)(m0 + lr) * 1024 + k0 + lc;
        const float* gw = W + (size_t)(n0 + lr) * 1024 + k0 + lc;
        float4 a0 = *(const float4*)ga;
        float4 a1 = *(const float4*)(ga + 4);
        float4 w0 = *(const float4*)gw;
        float4 w1 = *(const float4*)(gw + 4);
        *(bf16x8*)&sA[lr * SSTR + lc] = cvt8(a0, a1);
        *(bf16x8*)&sB[lr * SSTR + lc] = cvt8(w0, w1);
        __syncthreads();
        bf16x8 af[2], bfv[2];
        af[0]  = *(bf16x8*)&sA[(wr + l16) * SSTR + quad * 8];
        af[1]  = *(bf16x8*)&sA[(wr + 16 + l16) * SSTR + quad * 8];
        bfv[0] = *(bf16x8*)&sB[(wc + l16) * SSTR + quad * 8];
        bfv[1] = *(bf16x8*)&sB[(wc + 16 + l16) * SSTR + quad * 8];
#pragma unroll
        for (int mf = 0; mf < 2; mf++)
#pragma unroll
            for (int nf = 0; nf < 2; nf++)
                acc[mf][nf] = mfma16(af[mf], bfv[nf], acc[mf][nf]);
        __syncthreads();
    }
#pragma unroll
    for (int mf = 0; mf < 2; mf++)
#pragma unroll
        for (int nf = 0; nf < 2; nf++) {
            int col = n0 + wc + nf * 16 + l16;
            float bsum = bias1[col] + (bias2 ? bias2[col] : 0.0f);
#pragma unroll
            for (int r = 0; r < 4; r++) {
                int row = m0 + wr + mf * 16 + quad * 4 + r;
                C[(size_t)row * 1024 + col] = (bf16)((acc[mf][nf][r] + bsum) * scale);
            }
        }
}

// ---------------------------------------------------------------------------
// transposes: vb [b][s][d] -> vtb [b][d][s]   (bf16 out for flash fallback,
//                                              f16 out for the GEMM path)
// ---------------------------------------------------------------------------
__global__ __launch_bounds__(256) void transpose_v(
    const bf16* __restrict__ vb, bf16* __restrict__ vtb)
{
    __shared__ bf16 tile[32][33];
    const int b = blockIdx.z;
    const int s0 = blockIdx.x * 32, d0 = blockIdx.y * 32;
    const int tr = threadIdx.x >> 5;
    const int tc = threadIdx.x & 31;
#pragma unroll
    for (int k = 0; k < 4; k++) {
        int r = tr + k * 8;
        tile[r][tc] = vb[((size_t)b * S_ + s0 + r) * D_ + d0 + tc];
    }
    __syncthreads();
#pragma unroll
    for (int k = 0; k < 4; k++) {
        int r = tr + k * 8;
        vtb[((size_t)b * D_ + d0 + r) * S_ + s0 + tc] = tile[tc][r];
    }
}

__global__ __launch_bounds__(256) void transpose_v_f16(
    const bf16* __restrict__ vb, f16* __restrict__ vtb)
{
    __shared__ bf16 tile[32][33];
    const int b = blockIdx.z;
    const int s0 = blockIdx.x * 32, d0 = blockIdx.y * 32;
    const int tr = threadIdx.x >> 5;
    const int tc = threadIdx.x & 31;
#pragma unroll
    for (int k = 0; k < 4; k++) {
        int r = tr + k * 8;
        tile[r][tc] = vb[((size_t)b * S_ + s0 + r) * D_ + d0 + tc];
    }
    __syncthreads();
#pragma unroll
    for (int k = 0; k < 4; k++) {
        int r = tr + k * 8;
        vtb[((size_t)b * D_ + d0 + r) * S_ + s0 + tc] = (f16)(float)tile[tc][r];
    }
}

// ---------------------------------------------------------------------------
// m97-style GEMM: C[m][n] = sum_k A[m][k] * B[n][k], fp32 out.
// 128x128 tile, BK=32, global_load_lds width 16, 4 waves each 64x64.
// ---------------------------------------------------------------------------
template <typename T>
__global__ __launch_bounds__(256) void gemm_bt(
    const T* __restrict__ A, const T* __restrict__ B, float* __restrict__ C,
    int K, int ldc)
{
    using v8 = typename vec8_of<T>::type;
    __shared__ T sA[128 * 32];
    __shared__ T sB[128 * 32];
    const int tid = threadIdx.x;
    const int wave = tid >> 6, lane = tid & 63, quad = lane >> 4, l16 = lane & 15;
    const int m0 = blockIdx.x * 128, n0 = blockIdx.y * 128;
    const int wr = (wave >> 1) * 64, wc = (wave & 1) * 64;

    floatx4 acc[4][4];
#pragma unroll
    for (int i = 0; i < 4; i++)
#pragma unroll
        for (int j = 0; j < 4; j++) acc[i][j] = (floatx4)0.0f;

    for (int k0 = 0; k0 < K; k0 += 32) {
#pragma unroll
        for (int j = 0; j < 2; j++) {
            int idx = j * 256 + tid;
            int r = idx >> 2, c = (idx & 3) * 8;
            __builtin_amdgcn_global_load_lds(
                (const __attribute__((address_space(1))) void*)(A + (size_t)(m0 + r) * K + k0 + c),
                (__attribute__((address_space(3))) void*)(sA + idx * 8), 16, 0, 0);
            __builtin_amdgcn_global_load_lds(
                (const __attribute__((address_space(1))) void*)(B + (size_t)(n0 + r) * K + k0 + c),
                (__attribute__((address_space(3))) void*)(sB + idx * 8), 16, 0, 0);
        }
        __syncthreads();
        v8 af[4], bfv[4];
#pragma unroll
        for (int i = 0; i < 4; i++) {
            af[i]  = *(const v8*)&sA[(wr + i * 16 + l16) * 32 + quad * 8];
            bfv[i] = *(const v8*)&sB[(wc + i * 16 + l16) * 32 + quad * 8];
        }
#pragma unroll
        for (int mf = 0; mf < 4; mf++)
#pragma unroll
            for (int nf = 0; nf < 4; nf++)
                acc[mf][nf] = mfma_any(af[mf], bfv[nf], acc[mf][nf]);
        __syncthreads();
    }

#pragma unroll
    for (int mf = 0; mf < 4; mf++)
#pragma unroll
        for (int nf = 0; nf < 4; nf++) {
            int col = n0 + wc + nf * 16 + l16;
#pragma unroll
            for (int r = 0; r < 4; r++) {
                int row = m0 + wr + mf * 16 + quad * 4 + r;
                C[(size_t)row * ldc + col] = acc[mf][nf][r];
            }
        }
}

// ---------------------------------------------------------------------------
// softmax over one score row (4096 fp32) -> normalized fp16
// ---------------------------------------------------------------------------
__global__ __launch_bounds__(256) void softmax_row(
    const float* __restrict__ Sc, f16* __restrict__ P)
{
    const int q = blockIdx.x;
    const float* row = Sc + (size_t)q * S_;
    f16* prow = P + (size_t)q * S_;
    const int tid = threadIdx.x, wave = tid >> 6, lane = tid & 63;

    float4 v[4];
#pragma unroll
    for (int i = 0; i < 4; i++) v[i] = *(const float4*)(row + tid * 16 + i * 4);

    float m = -1e30f;
#pragma unroll
    for (int i = 0; i < 4; i++) {
        m = fmaxf(m, fmaxf(fmaxf(v[i].x, v[i].y), fmaxf(v[i].z, v[i].w)));
    }
#pragma unroll
    for (int off = 32; off; off >>= 1) m = fmaxf(m, __shfl_xor(m, off));
    __shared__ float redm[4], redl[4];
    if (lane == 0) redm[wave] = m;
    __syncthreads();
    m = fmaxf(fmaxf(redm[0], redm[1]), fmaxf(redm[2], redm[3]));

    float p[16];
    float s = 0.0f;
#pragma unroll
    for (int i = 0; i < 4; i++) {
        p[i * 4 + 0] = __expf(v[i].x - m);
        p[i * 4 + 1] = __expf(v[i].y - m);
        p[i * 4 + 2] = __expf(v[i].z - m);
        p[i * 4 + 3] = __expf(v[i].w - m);
        s += p[i * 4] + p[i * 4 + 1] + p[i * 4 + 2] + p[i * 4 + 3];
    }
#pragma unroll
    for (int off = 32; off; off >>= 1) s += __shfl_xor(s, off);
    if (lane == 0) redl[wave] = s;
    __syncthreads();
    s = redl[0] + redl[1] + redl[2] + redl[3];
    float inv = 1.0f / s;

    f16x8 o0, o1;
#pragma unroll
    for (int j = 0; j < 8; j++) {
        o0[j] = (f16)(p[j] * inv);
        o1[j] = (f16)(p[8 + j] * inv);
    }
    *(f16x8*)(prow + tid * 16) = o0;
    *(f16x8*)(prow + tid * 16 + 8) = o1;
}

// ---------------------------------------------------------------------------
// flash fallback (round-1 kernel, used only if ws is too small)
// ---------------------------------------------------------------------------
#define BR 32
#define TK 64
#define DC 256
__global__ __launch_bounds__(256, 2) void flash_attn(
    const bf16* __restrict__ qb, const bf16* __restrict__ vb,
    const bf16* __restrict__ vtb, float* __restrict__ out)
{
    __shared__ float sPart[4][32][65];
    __shared__ bf16 sP[32][72];
    __shared__ float sM[32], sL[32], sAlpha[32];

    const int tid = threadIdx.x;
    const int wave = tid >> 6, lane = tid & 63, quad = lane >> 4, l16 = lane & 15;
    const int b = blockIdx.y, q0 = blockIdx.x * BR;

    bf16x8 qf[2][8];
#pragma unroll
    for (int mf = 0; mf < 2; mf++)
#pragma unroll
        for (int ks = 0; ks < 8; ks++) {
            int row = q0 + mf * 16 + l16;
            int col = wave * DC + ks * 32 + quad * 8;
            qf[mf][ks] = *(const bf16x8*)(qb + ((size_t)b * S_ + row) * D_ + col);
        }

    floatx4 o[2][16];
#pragma unroll
    for (int mf = 0; mf < 2; mf++)
#pragma unroll
        for (int nf = 0; nf < 16; nf++) o[mf][nf] = (floatx4)0.0f;

    if (tid < 32) { sM[tid] = -1e30f; sL[tid] = 0.0f; }
    __syncthreads();

    for (int kt = 0; kt < S_ / TK; kt++) {
        const int k0 = kt * TK;
        floatx4 sp[2][4];
#pragma unroll
        for (int mf = 0; mf < 2; mf++)
#pragma unroll
            for (int nf = 0; nf < 4; nf++) sp[mf][nf] = (floatx4)0.0f;
#pragma unroll
        for (int ks = 0; ks < 8; ks++) {
            int col = wave * DC + ks * 32 + quad * 8;
#pragma unroll
            for (int nf = 0; nf < 4; nf++) {
                int key = k0 + nf * 16 + l16;
                bf16x8 vf = *(const bf16x8*)(vb + ((size_t)b * S_ + key) * D_ + col);
                sp[0][nf] = mfma16(qf[0][ks], vf, sp[0][nf]);
                sp[1][nf] = mfma16(qf[1][ks], vf, sp[1][nf]);
            }
        }
#pragma unroll
        for (int mf = 0; mf < 2; mf++)
#pragma unroll
            for (int nf = 0; nf < 4; nf++)
#pragma unroll
                for (int r = 0; r < 4; r++)
                    sPart[wave][mf * 16 + quad * 4 + r][nf * 16 + l16] = sp[mf][nf][r];
        __syncthreads();

        {
            const int rr = tid >> 3, c0 = (tid & 7) * 8;
            float v[8];
            float mx = -1e30f;
#pragma unroll
            for (int j = 0; j < 8; j++) {
                v[j] = sPart[0][rr][c0 + j] + sPart[1][rr][c0 + j] +
                       sPart[2][rr][c0 + j] + sPart[3][rr][c0 + j];
                mx = fmaxf(mx, v[j]);
            }
            mx = fmaxf(mx, __shfl_xor(mx, 1));
            mx = fmaxf(mx, __shfl_xor(mx, 2));
            mx = fmaxf(mx, __shfl_xor(mx, 4));
            float m_old = sM[rr];
            float m_new = fmaxf(m_old, mx);
            float rsum = 0.0f;
#pragma unroll
            for (int j = 0; j < 8; j++) {
                float p = __expf(v[j] - m_new);
                sP[rr][c0 + j] = (bf16)p;
                rsum += p;
            }
            rsum += __shfl_xor(rsum, 1);
            rsum += __shfl_xor(rsum, 2);
            rsum += __shfl_xor(rsum, 4);
            if ((tid & 7) == 0) {
                float alpha = __expf(m_old - m_new);
                sAlpha[rr] = alpha;
                sM[rr] = m_new;
                sL[rr] = sL[rr] * alpha + rsum;
            }
        }
        __syncthreads();

        float al[2][4];
#pragma unroll
        for (int mf = 0; mf < 2; mf++)
#pragma unroll
            for (int r = 0; r < 4; r++) al[mf][r] = sAlpha[mf * 16 + quad * 4 + r];
#pragma unroll
        for (int mf = 0; mf < 2; mf++)
#pragma unroll
            for (int nf = 0; nf < 16; nf++)
#pragma unroll
                for (int r = 0; r < 4; r++) o[mf][nf][r] *= al[mf][r];

#pragma unroll
        for (int ks2 = 0; ks2 < 2; ks2++) {
            bf16x8 pA[2];
            pA[0] = *(bf16x8*)&sP[l16][ks2 * 32 + quad * 8];
            pA[1] = *(bf16x8*)&sP[16 + l16][ks2 * 32 + quad * 8];
            int key = k0 + ks2 * 32 + quad * 8;
#pragma unroll
            for (int nf = 0; nf < 16; nf++) {
                int d = wave * DC + nf * 16 + l16;
                bf16x8 vtf = *(const bf16x8*)(vtb + ((size_t)b * D_ + d) * S_ + key);
                o[0][nf] = mfma16(pA[0], vtf, o[0][nf]);
                o[1][nf] = mfma16(pA[1], vtf, o[1][nf]);
            }
        }
        __syncthreads();
    }

#pragma unroll
    for (int mf = 0; mf < 2; mf++) {
        float inv[4];
#pragma unroll
        for (int r = 0; r < 4; r++) inv[r] = 1.0f / sL[mf * 16 + quad * 4 + r];
#pragma unroll
        for (int nf = 0; nf < 16; nf++) {
            int d = wave * DC + nf * 16 + l16;
#pragma unroll
            for (int r = 0; r < 4; r++) {
                int row = q0 + mf * 16 + quad * 4 + r;
                out[((size_t)b * S_ + row) * D_ + d] = o[mf][nf][r] * inv[r];
            }
        }
    }
}

// ---------------------------------------------------------------------------
extern "C" void kernel_launch(void* const* d_in, const int* in_sizes, int n_in,
                              void* d_out, int out_size, void* d_ws, size_t ws_size,
                              hipStream_t stream) {
    const float* query = (const float*)d_in[0];
    const float* value = (const float*)d_in[1];
    const float* Wq    = (const float*)d_in[2];
    const float* bq    = (const float*)d_in[3];
    const float* qk_b  = (const float*)d_in[4];
    const float* Wv    = (const float*)d_in[5];
    const float* bv    = (const float*)d_in[6];
    float* out = (float*)d_out;

    const size_t SD = (size_t)S_ * D_;        // 4.19M elems
    const size_t MB = 1024 * 1024;

    char* w = (char*)d_ws;
    bf16* qb = (bf16*)w;                       // 32 MB (bf16, scale+bias folded)
    bf16* vb = (bf16*)(w + 32 * MB);           // 32 MB

    dim3 pg(16384 / 64, 1024 / 64);
    proj_gemm<<<pg, 256, 0, stream>>>(query, Wq, bq, qk_b, qb, 0.125f);
    proj_gemm<<<pg, 256, 0, stream>>>(value, Wv, bv, nullptr, vb, 1.0f);

    if (ws_size >= 192 * MB) {
        // --- GEMM path: scores fp32 in ws, softmax -> fp16 P, PV GEMM ---
        f16*   vtb = (f16*)(w + 64 * MB);      // 32 MB [b][d][s] fp16
        float* Sc  = (float*)(w + 96 * MB);    // 64 MB fp32 scores (one batch)
        f16*   Pn  = (f16*)(w + 160 * MB);     // 32 MB fp16 normalized P

        transpose_v_f16<<<dim3(S_ / 32, D_ / 32, B_), 256, 0, stream>>>(vb, vtb);
        for (int b = 0; b < B_; b++) {
            gemm_bt<bf16><<<dim3(32, 32), 256, 0, stream>>>(
                qb + b * SD, vb + b * SD, Sc, D_, S_);
            softmax_row<<<S_, 256, 0, stream>>>(Sc, Pn);
            gemm_bt<f16><<<dim3(32, 8), 256, 0, stream>>>(
                Pn, vtb + (size_t)b * D_ * S_, out + b * SD, S_, D_);
        }
    } else {
        // --- fallback: round-1 flash path (96 MB ws) ---
        bf16* vtb = (bf16*)(w + 64 * MB);
        transpose_v<<<dim3(S_ / 32, D_ / 32, B_), 256, 0, stream>>>(vb, vtb);
        flash_attn<<<dim3(S_ / BR, B_), 256, 0, stream>>>(qb, vb, vtb, out);
    }
}

// Round 3
// 738.988 us; speedup vs baseline: 2.8708x; 1.5048x over previous
//
#include <hip/hip_runtime.h>

#define B_ 4
#define S_ 4096
#define D_ 1024

typedef __bf16 bf16;
typedef _Float16 f16;
typedef __attribute__((ext_vector_type(8))) __bf16 bf16x8;
typedef __attribute__((ext_vector_type(8))) _Float16 f16x8;
typedef __attribute__((ext_vector_type(4))) float floatx4;

__device__ inline floatx4 mfma16(bf16x8 a, bf16x8 b, floatx4 c) {
    return __builtin_amdgcn_mfma_f32_16x16x32_bf16(a, b, c, 0, 0, 0);
}
__device__ inline floatx4 mfma_any(bf16x8 a, bf16x8 b, floatx4 c) {
    return __builtin_amdgcn_mfma_f32_16x16x32_bf16(a, b, c, 0, 0, 0);
}
__device__ inline floatx4 mfma_any(f16x8 a, f16x8 b, floatx4 c) {
    return __builtin_amdgcn_mfma_f32_16x16x32_f16(a, b, c, 0, 0, 0);
}

template <typename T> struct vec8_of;
template <> struct vec8_of<bf16> { using type = bf16x8; };
template <> struct vec8_of<f16>  { using type = f16x8; };

__device__ inline bf16x8 cvt8(float4 a, float4 b) {
    bf16x8 h;
    h[0] = (bf16)a.x; h[1] = (bf16)a.y; h[2] = (bf16)a.z; h[3] = (bf16)a.w;
    h[4] = (bf16)b.x; h[5] = (bf16)b.y; h[6] = (bf16)b.z; h[7] = (bf16)b.w;
    return h;
}

// ---------------------------------------------------------------------------
// elementwise fp32 -> bf16 cast (n multiple of 2048)
// ---------------------------------------------------------------------------
__global__ __launch_bounds__(256) void cast_f32_bf16(
    const float* __restrict__ in, bf16* __restrict__ out)
{
    size_t i = ((size_t)blockIdx.x * 256 + threadIdx.x) * 8;
    float4 a = *(const float4*)(in + i);
    float4 b = *(const float4*)(in + i + 4);
    *(bf16x8*)(out + i) = cvt8(a, b);
}

// ---------------------------------------------------------------------------
// Unified m97-style GEMM: C[m][n] = op( sum_k A[m][k]*B[n][k] )
// 128x128 tile, BK=32, global_load_lds width 16, 4 waves each 64x64.
// blockIdx.z offsets A/B/C by the given element strides (batching).
// HAS_BIAS: C = (acc + bias1[n] + bias2?[n]) * scale
// ---------------------------------------------------------------------------
template <typename TI, typename TO, bool HAS_BIAS>
__global__ __launch_bounds__(256) void gemm128(
    const TI* __restrict__ A, const TI* __restrict__ B, TO* __restrict__ C,
    int K, int ldc, size_t strideA, size_t strideB, size_t strideC,
    const float* __restrict__ bias1, const float* __restrict__ bias2, float scale)
{
    using v8 = typename vec8_of<TI>::type;
    __shared__ TI sA[128 * 32];
    __shared__ TI sB[128 * 32];
    A += (size_t)blockIdx.z * strideA;
    B += (size_t)blockIdx.z * strideB;
    C += (size_t)blockIdx.z * strideC;

    const int tid = threadIdx.x;
    const int wave = tid >> 6, lane = tid & 63, quad = lane >> 4, l16 = lane & 15;
    const int m0 = blockIdx.x * 128, n0 = blockIdx.y * 128;
    const int wr = (wave >> 1) * 64, wc = (wave & 1) * 64;

    floatx4 acc[4][4];
#pragma unroll
    for (int i = 0; i < 4; i++)
#pragma unroll
        for (int j = 0; j < 4; j++) acc[i][j] = (floatx4)0.0f;

    for (int k0 = 0; k0 < K; k0 += 32) {
#pragma unroll
        for (int j = 0; j < 2; j++) {
            int idx = j * 256 + tid;
            int r = idx >> 2, c = (idx & 3) * 8;
            __builtin_amdgcn_global_load_lds(
                (const __attribute__((address_space(1))) void*)(A + (size_t)(m0 + r) * K + k0 + c),
                (__attribute__((address_space(3))) void*)(sA + idx * 8), 16, 0, 0);
            __builtin_amdgcn_global_load_lds(
                (const __attribute__((address_space(1))) void*)(B + (size_t)(n0 + r) * K + k0 + c),
                (__attribute__((address_space(3))) void*)(sB + idx * 8), 16, 0, 0);
        }
        __syncthreads();
        v8 af[4], bfv[4];
#pragma unroll
        for (int i = 0; i < 4; i++) {
            af[i]  = *(const v8*)&sA[(wr + i * 16 + l16) * 32 + quad * 8];
            bfv[i] = *(const v8*)&sB[(wc + i * 16 + l16) * 32 + quad * 8];
        }
#pragma unroll
        for (int mf = 0; mf < 4; mf++)
#pragma unroll
            for (int nf = 0; nf < 4; nf++)
                acc[mf][nf] = mfma_any(af[mf], bfv[nf], acc[mf][nf]);
        __syncthreads();
    }

#pragma unroll
    for (int mf = 0; mf < 4; mf++)
#pragma unroll
        for (int nf = 0; nf < 4; nf++) {
            int col = n0 + wc + nf * 16 + l16;
            float badd = 0.0f;
            if (HAS_BIAS) {
                badd = bias1[col];
                if (bias2) badd += bias2[col];
            }
#pragma unroll
            for (int r = 0; r < 4; r++) {
                int row = m0 + wr + mf * 16 + quad * 4 + r;
                float v = acc[mf][nf][r];
                if (HAS_BIAS) v = (v + badd) * scale;
                C[(size_t)row * ldc + col] = (TO)v;
            }
        }
}

// ---------------------------------------------------------------------------
// transposes: vb [b][s][d] -> vtb [b][d][s]
// ---------------------------------------------------------------------------
__global__ __launch_bounds__(256) void transpose_v(
    const bf16* __restrict__ vb, bf16* __restrict__ vtb)
{
    __shared__ bf16 tile[32][33];
    const int b = blockIdx.z;
    const int s0 = blockIdx.x * 32, d0 = blockIdx.y * 32;
    const int tr = threadIdx.x >> 5;
    const int tc = threadIdx.x & 31;
#pragma unroll
    for (int k = 0; k < 4; k++) {
        int r = tr + k * 8;
        tile[r][tc] = vb[((size_t)b * S_ + s0 + r) * D_ + d0 + tc];
    }
    __syncthreads();
#pragma unroll
    for (int k = 0; k < 4; k++) {
        int r = tr + k * 8;
        vtb[((size_t)b * D_ + d0 + r) * S_ + s0 + tc] = tile[tc][r];
    }
}

__global__ __launch_bounds__(256) void transpose_v_f16(
    const bf16* __restrict__ vb, f16* __restrict__ vtb)
{
    __shared__ bf16 tile[32][33];
    const int b = blockIdx.z;
    const int s0 = blockIdx.x * 32, d0 = blockIdx.y * 32;
    const int tr = threadIdx.x >> 5;
    const int tc = threadIdx.x & 31;
#pragma unroll
    for (int k = 0; k < 4; k++) {
        int r = tr + k * 8;
        tile[r][tc] = vb[((size_t)b * S_ + s0 + r) * D_ + d0 + tc];
    }
    __syncthreads();
#pragma unroll
    for (int k = 0; k < 4; k++) {
        int r = tr + k * 8;
        vtb[((size_t)b * D_ + d0 + r) * S_ + s0 + tc] = (f16)(float)tile[tc][r];
    }
}

// ---------------------------------------------------------------------------
// softmax over one 4096-row of f16 scores, in place (normalized f16 out)
// ---------------------------------------------------------------------------
__global__ __launch_bounds__(256) void softmax_inplace_f16(f16* __restrict__ Sc)
{
    f16* row = Sc + (size_t)blockIdx.x * S_;
    const int tid = threadIdx.x, wave = tid >> 6, lane = tid & 63;
    __shared__ float redm[4], redl[4];

    f16x8 a = *(const f16x8*)(row + tid * 16);
    f16x8 b = *(const f16x8*)(row + tid * 16 + 8);
    float v[16];
#pragma unroll
    for (int j = 0; j < 8; j++) { v[j] = (float)a[j]; v[8 + j] = (float)b[j]; }

    float m = -1e30f;
#pragma unroll
    for (int j = 0; j < 16; j++) m = fmaxf(m, v[j]);
#pragma unroll
    for (int off = 32; off; off >>= 1) m = fmaxf(m, __shfl_xor(m, off));
    if (lane == 0) redm[wave] = m;
    __syncthreads();
    m = fmaxf(fmaxf(redm[0], redm[1]), fmaxf(redm[2], redm[3]));

    float s = 0.0f;
#pragma unroll
    for (int j = 0; j < 16; j++) { v[j] = __expf(v[j] - m); s += v[j]; }
#pragma unroll
    for (int off = 32; off; off >>= 1) s += __shfl_xor(s, off);
    if (lane == 0) redl[wave] = s;
    __syncthreads();
    s = redl[0] + redl[1] + redl[2] + redl[3];
    float inv = 1.0f / s;

#pragma unroll
    for (int j = 0; j < 8; j++) { a[j] = (f16)(v[j] * inv); b[j] = (f16)(v[8 + j] * inv); }
    *(f16x8*)(row + tid * 16) = a;
    *(f16x8*)(row + tid * 16 + 8) = b;
}

// ---------------------------------------------------------------------------
// softmax over one fp32 score row -> normalized fp16 (per-batch fallback)
// ---------------------------------------------------------------------------
__global__ __launch_bounds__(256) void softmax_row(
    const float* __restrict__ Sc, f16* __restrict__ P)
{
    const int q = blockIdx.x;
    const float* row = Sc + (size_t)q * S_;
    f16* prow = P + (size_t)q * S_;
    const int tid = threadIdx.x, wave = tid >> 6, lane = tid & 63;

    float4 v[4];
#pragma unroll
    for (int i = 0; i < 4; i++) v[i] = *(const float4*)(row + tid * 16 + i * 4);

    float m = -1e30f;
#pragma unroll
    for (int i = 0; i < 4; i++)
        m = fmaxf(m, fmaxf(fmaxf(v[i].x, v[i].y), fmaxf(v[i].z, v[i].w)));
#pragma unroll
    for (int off = 32; off; off >>= 1) m = fmaxf(m, __shfl_xor(m, off));
    __shared__ float redm[4], redl[4];
    if (lane == 0) redm[wave] = m;
    __syncthreads();
    m = fmaxf(fmaxf(redm[0], redm[1]), fmaxf(redm[2], redm[3]));

    float p[16];
    float s = 0.0f;
#pragma unroll
    for (int i = 0; i < 4; i++) {
        p[i * 4 + 0] = __expf(v[i].x - m);
        p[i * 4 + 1] = __expf(v[i].y - m);
        p[i * 4 + 2] = __expf(v[i].z - m);
        p[i * 4 + 3] = __expf(v[i].w - m);
        s += p[i * 4] + p[i * 4 + 1] + p[i * 4 + 2] + p[i * 4 + 3];
    }
#pragma unroll
    for (int off = 32; off; off >>= 1) s += __shfl_xor(s, off);
    if (lane == 0) redl[wave] = s;
    __syncthreads();
    s = redl[0] + redl[1] + redl[2] + redl[3];
    float inv = 1.0f / s;

    f16x8 o0, o1;
#pragma unroll
    for (int j = 0; j < 8; j++) {
        o0[j] = (f16)(p[j] * inv);
        o1[j] = (f16)(p[8 + j] * inv);
    }
    *(f16x8*)(prow + tid * 16) = o0;
    *(f16x8*)(prow + tid * 16 + 8) = o1;
}

// ---------------------------------------------------------------------------
// legacy fp32-input proj (flash fallback only)
// ---------------------------------------------------------------------------
#define SSTR 40
__global__ __launch_bounds__(256) void proj_gemm(
    const float* __restrict__ A, const float* __restrict__ W,
    const float* __restrict__ bias1, const float* __restrict__ bias2,
    bf16* __restrict__ C, float scale)
{
    __shared__ bf16 sA[64 * SSTR];
    __shared__ bf16 sB[64 * SSTR];
    const int tid = threadIdx.x;
    const int wave = tid >> 6, lane = tid & 63, quad = lane >> 4, l16 = lane & 15;
    const int m0 = blockIdx.x * 64, n0 = blockIdx.y * 64;
    const int wr = (wave >> 1) * 32, wc = (wave & 1) * 32;
    const int lr = tid >> 2;
    const int lc = (tid & 3) * 8;

    floatx4 acc[2][2];
#pragma unroll
    for (int i = 0; i < 2; i++)
#pragma unroll
        for (int j = 0; j < 2; j++) acc[i][j] = (floatx4)0.0f;

    for (int k0 = 0; k0 < 1024; k0 += 32) {
        const float* ga = A + (size_t)(m0 + lr) * 1024 + k0 + lc;
        const float* gw = W + (size_t)(n0 + lr) * 1024 + k0 + lc;
        float4 a0 = *(const float4*)ga;
        float4 a1 = *(const float4*)(ga + 4);
        float4 w0 = *(const float4*)gw;
        float4 w1 = *(const float4*)(gw + 4);
        *(bf16x8*)&sA[lr * SSTR + lc] = cvt8(a0, a1);
        *(bf16x8*)&sB[lr * SSTR + lc] = cvt8(w0, w1);
        __syncthreads();
        bf16x8 af[2], bfv[2];
        af[0]  = *(bf16x8*)&sA[(wr + l16) * SSTR + quad * 8];
        af[1]  = *(bf16x8*)&sA[(wr + 16 + l16) * SSTR + quad * 8];
        bfv[0] = *(bf16x8*)&sB[(wc + l16) * SSTR + quad * 8];
        bfv[1] = *(bf16x8*)&sB[(wc + 16 + l16) * SSTR + quad * 8];
#pragma unroll
        for (int mf = 0; mf < 2; mf++)
#pragma unroll
            for (int nf = 0; nf < 2; nf++)
                acc[mf][nf] = mfma16(af[mf], bfv[nf], acc[mf][nf]);
        __syncthreads();
    }
#pragma unroll
    for (int mf = 0; mf < 2; mf++)
#pragma unroll
        for (int nf = 0; nf < 2; nf++) {
            int col = n0 + wc + nf * 16 + l16;
            float bsum = bias1[col] + (bias2 ? bias2[col] : 0.0f);
#pragma unroll
            for (int r = 0; r < 4; r++) {
                int row = m0 + wr + mf * 16 + quad * 4 + r;
                C[(size_t)row * 1024 + col] = (bf16)((acc[mf][nf][r] + bsum) * scale);
            }
        }
}

// ---------------------------------------------------------------------------
// flash fallback (only if ws < 192MB)
// ---------------------------------------------------------------------------
#define BR 32
#define TK 64
#define DC 256
__global__ __launch_bounds__(256, 2) void flash_attn(
    const bf16* __restrict__ qb, const bf16* __restrict__ vb,
    const bf16* __restrict__ vtb, float* __restrict__ out)
{
    __shared__ float sPart[4][32][65];
    __shared__ bf16 sP[32][72];
    __shared__ float sM[32], sL[32], sAlpha[32];

    const int tid = threadIdx.x;
    const int wave = tid >> 6, lane = tid & 63, quad = lane >> 4, l16 = lane & 15;
    const int b = blockIdx.y, q0 = blockIdx.x * BR;

    bf16x8 qf[2][8];
#pragma unroll
    for (int mf = 0; mf < 2; mf++)
#pragma unroll
        for (int ks = 0; ks < 8; ks++) {
            int row = q0 + mf * 16 + l16;
            int col = wave * DC + ks * 32 + quad * 8;
            qf[mf][ks] = *(const bf16x8*)(qb + ((size_t)b * S_ + row) * D_ + col);
        }

    floatx4 o[2][16];
#pragma unroll
    for (int mf = 0; mf < 2; mf++)
#pragma unroll
        for (int nf = 0; nf < 16; nf++) o[mf][nf] = (floatx4)0.0f;

    if (tid < 32) { sM[tid] = -1e30f; sL[tid] = 0.0f; }
    __syncthreads();

    for (int kt = 0; kt < S_ / TK; kt++) {
        const int k0 = kt * TK;
        floatx4 sp[2][4];
#pragma unroll
        for (int mf = 0; mf < 2; mf++)
#pragma unroll
            for (int nf = 0; nf < 4; nf++) sp[mf][nf] = (floatx4)0.0f;
#pragma unroll
        for (int ks = 0; ks < 8; ks++) {
            int col = wave * DC + ks * 32 + quad * 8;
#pragma unroll
            for (int nf = 0; nf < 4; nf++) {
                int key = k0 + nf * 16 + l16;
                bf16x8 vf = *(const bf16x8*)(vb + ((size_t)b * S_ + key) * D_ + col);
                sp[0][nf] = mfma16(qf[0][ks], vf, sp[0][nf]);
                sp[1][nf] = mfma16(qf[1][ks], vf, sp[1][nf]);
            }
        }
#pragma unroll
        for (int mf = 0; mf < 2; mf++)
#pragma unroll
            for (int nf = 0; nf < 4; nf++)
#pragma unroll
                for (int r = 0; r < 4; r++)
                    sPart[wave][mf * 16 + quad * 4 + r][nf * 16 + l16] = sp[mf][nf][r];
        __syncthreads();

        {
            const int rr = tid >> 3, c0 = (tid & 7) * 8;
            float v[8];
            float mx = -1e30f;
#pragma unroll
            for (int j = 0; j < 8; j++) {
                v[j] = sPart[0][rr][c0 + j] + sPart[1][rr][c0 + j] +
                       sPart[2][rr][c0 + j] + sPart[3][rr][c0 + j];
                mx = fmaxf(mx, v[j]);
            }
            mx = fmaxf(mx, __shfl_xor(mx, 1));
            mx = fmaxf(mx, __shfl_xor(mx, 2));
            mx = fmaxf(mx, __shfl_xor(mx, 4));
            float m_old = sM[rr];
            float m_new = fmaxf(m_old, mx);
            float rsum = 0.0f;
#pragma unroll
            for (int j = 0; j < 8; j++) {
                float p = __expf(v[j] - m_new);
                sP[rr][c0 + j] = (bf16)p;
                rsum += p;
            }
            rsum += __shfl_xor(rsum, 1);
            rsum += __shfl_xor(rsum, 2);
            rsum += __shfl_xor(rsum, 4);
            if ((tid & 7) == 0) {
                float alpha = __expf(m_old - m_new);
                sAlpha[rr] = alpha;
                sM[rr] = m_new;
                sL[rr] = sL[rr] * alpha + rsum;
            }
        }
        __syncthreads();

        float al[2][4];
#pragma unroll
        for (int mf = 0; mf < 2; mf++)
#pragma unroll
            for (int r = 0; r < 4; r++) al[mf][r] = sAlpha[mf * 16 + quad * 4 + r];
#pragma unroll
        for (int mf = 0; mf < 2; mf++)
#pragma unroll
            for (int nf = 0; nf < 16; nf++)
#pragma unroll
                for (int r = 0; r < 4; r++) o[mf][nf][r] *= al[mf][r];

#pragma unroll
        for (int ks2 = 0; ks2 < 2; ks2++) {
            bf16x8 pA[2];
            pA[0] = *(bf16x8*)&sP[l16][ks2 * 32 + quad * 8];
            pA[1] = *(bf16x8*)&sP[16 + l16][ks2 * 32 + quad * 8];
            int key = k0 + ks2 * 32 + quad * 8;
#pragma unroll
            for (int nf = 0; nf < 16; nf++) {
                int d = wave * DC + nf * 16 + l16;
                bf16x8 vtf = *(const bf16x8*)(vtb + ((size_t)b * D_ + d) * S_ + key);
                o[0][nf] = mfma16(pA[0], vtf, o[0][nf]);
                o[1][nf] = mfma16(pA[1], vtf, o[1][nf]);
            }
        }
        __syncthreads();
    }

#pragma unroll
    for (int mf = 0; mf < 2; mf++) {
        float inv[4];
#pragma unroll
        for (int r = 0; r < 4; r++) inv[r] = 1.0f / sL[mf * 16 + quad * 4 + r];
#pragma unroll
        for (int nf = 0; nf < 16; nf++) {
            int d = wave * DC + nf * 16 + l16;
#pragma unroll
            for (int r = 0; r < 4; r++) {
                int row = q0 + mf * 16 + quad * 4 + r;
                out[((size_t)b * S_ + row) * D_ + d] = o[mf][nf][r] * inv[r];
            }
        }
    }
}

// ---------------------------------------------------------------------------
extern "C" void kernel_launch(void* const* d_in, const int* in_sizes, int n_in,
                              void* d_out, int out_size, void* d_ws, size_t ws_size,
                              hipStream_t stream) {
    const float* query = (const float*)d_in[0];
    const float* value = (const float*)d_in[1];
    const float* Wq    = (const float*)d_in[2];
    const float* bq    = (const float*)d_in[3];
    const float* qk_b  = (const float*)d_in[4];
    const float* Wv    = (const float*)d_in[5];
    const float* bv    = (const float*)d_in[6];
    float* out = (float*)d_out;

    const size_t SD = (size_t)S_ * D_;   // 4.19M elems
    const size_t SS = (size_t)S_ * S_;   // 16.8M elems
    const size_t MB = 1024 * 1024;

    char* w = (char*)d_ws;
    bf16* qb = (bf16*)w;                  // 32 MB (scale+bias folded)
    bf16* vb = (bf16*)(w + 32 * MB);      // 32 MB

    if (ws_size >= 224 * MB) {
        // ---- full batched path ----
        f16* vtb = (f16*)(w + 64 * MB);   // 32 MB [b][d][s]
        f16* Sc  = (f16*)(w + 96 * MB);   // 128 MB [b][q][k]; softmax in place
        // cast scratch aliases into the (not yet written) Sc region:
        bf16* qc  = (bf16*)(w + 96 * MB);   // 32 MB
        bf16* vc  = (bf16*)(w + 128 * MB);  // 32 MB
        bf16* wqc = (bf16*)(w + 160 * MB);  // 2 MB
        bf16* wvc = (bf16*)(w + 163 * MB);  // 2 MB

        cast_f32_bf16<<<(B_ * SD) / 2048, 256, 0, stream>>>(query, qc);
        cast_f32_bf16<<<(B_ * SD) / 2048, 256, 0, stream>>>(value, vc);
        cast_f32_bf16<<<((size_t)D_ * D_) / 2048, 256, 0, stream>>>(Wq, wqc);
        cast_f32_bf16<<<((size_t)D_ * D_) / 2048, 256, 0, stream>>>(Wv, wvc);

        // projections: [16384 x 1024] = [16384 x 1024] . [1024 x 1024]^T
        gemm128<bf16, bf16, true><<<dim3(128, 8, 1), 256, 0, stream>>>(
            qc, wqc, qb, D_, D_, 0, 0, 0, bq, qk_b, 0.125f);
        gemm128<bf16, bf16, true><<<dim3(128, 8, 1), 256, 0, stream>>>(
            vc, wvc, vb, D_, D_, 0, 0, 0, bv, nullptr, 1.0f);

        transpose_v_f16<<<dim3(S_ / 32, D_ / 32, B_), 256, 0, stream>>>(vb, vtb);

        // scores (all batches): Sc[b][q][k] = qb[b][q][:] . vb[b][k][:]
        gemm128<bf16, f16, false><<<dim3(32, 32, B_), 256, 0, stream>>>(
            qb, vb, Sc, D_, S_, SD, SD, SS, nullptr, nullptr, 1.0f);

        softmax_inplace_f16<<<B_ * S_, 256, 0, stream>>>(Sc);

        // O (all batches): out[b][q][d] = P[b][q][:] . vtb[b][d][:]
        gemm128<f16, float, false><<<dim3(32, 8, B_), 256, 0, stream>>>(
            Sc, vtb, out, S_, D_, SS, (size_t)D_ * S_, SD, nullptr, nullptr, 1.0f);
    } else if (ws_size >= 192 * MB) {
        // ---- per-batch fallback (fp32 scores) ----
        f16*   vtb = (f16*)(w + 64 * MB);     // 32 MB
        float* Sc  = (float*)(w + 96 * MB);   // 64 MB (one batch)
        f16*   Pn  = (f16*)(w + 160 * MB);    // 32 MB
        bf16*  qc  = (bf16*)(w + 96 * MB);    // cast scratch aliases Sc/Pn
        bf16*  vc  = (bf16*)(w + 128 * MB);
        bf16*  wqc = (bf16*)(w + 160 * MB);
        bf16*  wvc = (bf16*)(w + 163 * MB);

        cast_f32_bf16<<<(B_ * SD) / 2048, 256, 0, stream>>>(query, qc);
        cast_f32_bf16<<<(B_ * SD) / 2048, 256, 0, stream>>>(value, vc);
        cast_f32_bf16<<<((size_t)D_ * D_) / 2048, 256, 0, stream>>>(Wq, wqc);
        cast_f32_bf16<<<((size_t)D_ * D_) / 2048, 256, 0, stream>>>(Wv, wvc);

        gemm128<bf16, bf16, true><<<dim3(128, 8, 1), 256, 0, stream>>>(
            qc, wqc, qb, D_, D_, 0, 0, 0, bq, qk_b, 0.125f);
        gemm128<bf16, bf16, true><<<dim3(128, 8, 1), 256, 0, stream>>>(
            vc, wvc, vb, D_, D_, 0, 0, 0, bv, nullptr, 1.0f);

        transpose_v_f16<<<dim3(S_ / 32, D_ / 32, B_), 256, 0, stream>>>(vb, vtb);

        for (int b = 0; b < B_; b++) {
            gemm128<bf16, float, false><<<dim3(32, 32, 1), 256, 0, stream>>>(
                qb + b * SD, vb + b * SD, Sc, D_, S_, 0, 0, 0, nullptr, nullptr, 1.0f);
            softmax_row<<<S_, 256, 0, stream>>>(Sc, Pn);
            gemm128<f16, float, false><<<dim3(32, 8, 1), 256, 0, stream>>>(
                Pn, vtb + (size_t)b * D_ * S_, out + b * SD, S_, D_,
                0, 0, 0, nullptr, nullptr, 1.0f);
        }
    } else {
        // ---- flash fallback (96 MB) ----
        bf16* vtb = (bf16*)(w + 64 * MB);
        dim3 pg(16384 / 64, 1024 / 64);
        proj_gemm<<<pg, 256, 0, stream>>>(query, Wq, bq, qk_b, qb, 0.125f);
        proj_gemm<<<pg, 256, 0, stream>>>(value, Wv, bv, nullptr, vb, 1.0f);
        transpose_v<<<dim3(S_ / 32, D_ / 32, B_), 256, 0, stream>>>(vb, vtb);
        flash_attn<<<dim3(S_ / BR, B_), 256, 0, stream>>>(qb, vb, vtb, out);
    }
}

// Round 4
// 677.309 us; speedup vs baseline: 3.1322x; 1.0911x over previous
//
#include <hip/hip_runtime.h>

#define B_ 4
#define S_ 4096
#define D_ 1024

typedef __bf16 bf16;
typedef _Float16 f16;
typedef __attribute__((ext_vector_type(8))) __bf16 bf16x8;
typedef __attribute__((ext_vector_type(8))) _Float16 f16x8;
typedef __attribute__((ext_vector_type(4))) float floatx4;

__device__ inline floatx4 mfma16(bf16x8 a, bf16x8 b, floatx4 c) {
    return __builtin_amdgcn_mfma_f32_16x16x32_bf16(a, b, c, 0, 0, 0);
}
__device__ inline floatx4 mfma_any(bf16x8 a, bf16x8 b, floatx4 c) {
    return __builtin_amdgcn_mfma_f32_16x16x32_bf16(a, b, c, 0, 0, 0);
}
__device__ inline floatx4 mfma_any(f16x8 a, f16x8 b, floatx4 c) {
    return __builtin_amdgcn_mfma_f32_16x16x32_f16(a, b, c, 0, 0, 0);
}

template <typename T> struct vec8_of;
template <> struct vec8_of<bf16> { using type = bf16x8; };
template <> struct vec8_of<f16>  { using type = f16x8; };

__device__ inline bf16x8 cvt8(float4 a, float4 b) {
    bf16x8 h;
    h[0] = (bf16)a.x; h[1] = (bf16)a.y; h[2] = (bf16)a.z; h[3] = (bf16)a.w;
    h[4] = (bf16)b.x; h[5] = (bf16)b.y; h[6] = (bf16)b.z; h[7] = (bf16)b.w;
    return h;
}

// ---------------------------------------------------------------------------
// elementwise fp32 -> bf16 cast (n multiple of 2048)
// ---------------------------------------------------------------------------
__global__ __launch_bounds__(256) void cast_f32_bf16(
    const float* __restrict__ in, bf16* __restrict__ out)
{
    size_t i = ((size_t)blockIdx.x * 256 + threadIdx.x) * 8;
    float4 a = *(const float4*)(in + i);
    float4 b = *(const float4*)(in + i + 4);
    *(bf16x8*)(out + i) = cvt8(a, b);
}

// ---------------------------------------------------------------------------
// m97-style GEMM, BK=64 as two 32-wide slabs (one barrier pair per 64-K).
// C[m][n] = op( sum_k A[m][k]*B[n][k] ). 128x128 tile, 4 waves each 64x64.
// LDS slab layout: [slab s][row 0..127][32 elems] — identical per-slab bank
// profile to the verified m97 BK=32 layout (global_load_lds forbids padding).
// blockIdx.z offsets A/B/C by the given element strides (batching).
// HAS_BIAS: C = (acc + bias1[n] + bias2?[n]) * scale
// ---------------------------------------------------------------------------
template <typename TI, typename TO, bool HAS_BIAS>
__global__ __launch_bounds__(256) void gemm128(
    const TI* __restrict__ A, const TI* __restrict__ B, TO* __restrict__ C,
    int K, int ldc, size_t strideA, size_t strideB, size_t strideC,
    const float* __restrict__ bias1, const float* __restrict__ bias2, float scale)
{
    using v8 = typename vec8_of<TI>::type;
    __shared__ TI sA[2 * 128 * 32];
    __shared__ TI sB[2 * 128 * 32];
    A += (size_t)blockIdx.z * strideA;
    B += (size_t)blockIdx.z * strideB;
    C += (size_t)blockIdx.z * strideC;

    const int tid = threadIdx.x;
    const int wave = tid >> 6, lane = tid & 63, quad = lane >> 4, l16 = lane & 15;
    const int m0 = blockIdx.x * 128, n0 = blockIdx.y * 128;
    const int wr = (wave >> 1) * 64, wc = (wave & 1) * 64;

    floatx4 acc[4][4];
#pragma unroll
    for (int i = 0; i < 4; i++)
#pragma unroll
        for (int j = 0; j < 4; j++) acc[i][j] = (floatx4)0.0f;

    for (int k0 = 0; k0 < K; k0 += 64) {
#pragma unroll
        for (int s = 0; s < 2; s++) {
#pragma unroll
            for (int j = 0; j < 2; j++) {
                int idx = j * 256 + tid;
                int r = idx >> 2, c = (idx & 3) * 8;
                __builtin_amdgcn_global_load_lds(
                    (const __attribute__((address_space(1))) void*)(A + (size_t)(m0 + r) * K + k0 + s * 32 + c),
                    (__attribute__((address_space(3))) void*)(sA + s * 4096 + idx * 8), 16, 0, 0);
                __builtin_amdgcn_global_load_lds(
                    (const __attribute__((address_space(1))) void*)(B + (size_t)(n0 + r) * K + k0 + s * 32 + c),
                    (__attribute__((address_space(3))) void*)(sB + s * 4096 + idx * 8), 16, 0, 0);
            }
        }
        __syncthreads();
#pragma unroll
        for (int s = 0; s < 2; s++) {
            v8 af[4], bfv[4];
#pragma unroll
            for (int i = 0; i < 4; i++) {
                af[i]  = *(const v8*)&sA[s * 4096 + (wr + i * 16 + l16) * 32 + quad * 8];
                bfv[i] = *(const v8*)&sB[s * 4096 + (wc + i * 16 + l16) * 32 + quad * 8];
            }
#pragma unroll
            for (int mf = 0; mf < 4; mf++)
#pragma unroll
                for (int nf = 0; nf < 4; nf++)
                    acc[mf][nf] = mfma_any(af[mf], bfv[nf], acc[mf][nf]);
        }
        __syncthreads();
    }

#pragma unroll
    for (int mf = 0; mf < 4; mf++)
#pragma unroll
        for (int nf = 0; nf < 4; nf++) {
            int col = n0 + wc + nf * 16 + l16;
            float badd = 0.0f;
            if (HAS_BIAS) {
                badd = bias1[col];
                if (bias2) badd += bias2[col];
            }
#pragma unroll
            for (int r = 0; r < 4; r++) {
                int row = m0 + wr + mf * 16 + quad * 4 + r;
                float v = acc[mf][nf][r];
                if (HAS_BIAS) v = (v + badd) * scale;
                C[(size_t)row * ldc + col] = (TO)v;
            }
        }
}

// ---------------------------------------------------------------------------
// transposes: vb [b][s][d] -> vtb [b][d][s]
// ---------------------------------------------------------------------------
__global__ __launch_bounds__(256) void transpose_v(
    const bf16* __restrict__ vb, bf16* __restrict__ vtb)
{
    __shared__ bf16 tile[32][33];
    const int b = blockIdx.z;
    const int s0 = blockIdx.x * 32, d0 = blockIdx.y * 32;
    const int tr = threadIdx.x >> 5;
    const int tc = threadIdx.x & 31;
#pragma unroll
    for (int k = 0; k < 4; k++) {
        int r = tr + k * 8;
        tile[r][tc] = vb[((size_t)b * S_ + s0 + r) * D_ + d0 + tc];
    }
    __syncthreads();
#pragma unroll
    for (int k = 0; k < 4; k++) {
        int r = tr + k * 8;
        vtb[((size_t)b * D_ + d0 + r) * S_ + s0 + tc] = tile[tc][r];
    }
}

__global__ __launch_bounds__(256) void transpose_v_f16(
    const bf16* __restrict__ vb, f16* __restrict__ vtb)
{
    __shared__ bf16 tile[32][33];
    const int b = blockIdx.z;
    const int s0 = blockIdx.x * 32, d0 = blockIdx.y * 32;
    const int tr = threadIdx.x >> 5;
    const int tc = threadIdx.x & 31;
#pragma unroll
    for (int k = 0; k < 4; k++) {
        int r = tr + k * 8;
        tile[r][tc] = vb[((size_t)b * S_ + s0 + r) * D_ + d0 + tc];
    }
    __syncthreads();
#pragma unroll
    for (int k = 0; k < 4; k++) {
        int r = tr + k * 8;
        vtb[((size_t)b * D_ + d0 + r) * S_ + s0 + tc] = (f16)(float)tile[tc][r];
    }
}

// ---------------------------------------------------------------------------
// softmax over one 4096-row of f16 scores, in place (normalized f16 out)
// ---------------------------------------------------------------------------
__global__ __launch_bounds__(256) void softmax_inplace_f16(f16* __restrict__ Sc)
{
    f16* row = Sc + (size_t)blockIdx.x * S_;
    const int tid = threadIdx.x, wave = tid >> 6, lane = tid & 63;
    __shared__ float redm[4], redl[4];

    f16x8 a = *(const f16x8*)(row + tid * 16);
    f16x8 b = *(const f16x8*)(row + tid * 16 + 8);
    float v[16];
#pragma unroll
    for (int j = 0; j < 8; j++) { v[j] = (float)a[j]; v[8 + j] = (float)b[j]; }

    float m = -1e30f;
#pragma unroll
    for (int j = 0; j < 16; j++) m = fmaxf(m, v[j]);
#pragma unroll
    for (int off = 32; off; off >>= 1) m = fmaxf(m, __shfl_xor(m, off));
    if (lane == 0) redm[wave] = m;
    __syncthreads();
    m = fmaxf(fmaxf(redm[0], redm[1]), fmaxf(redm[2], redm[3]));

    float s = 0.0f;
#pragma unroll
    for (int j = 0; j < 16; j++) { v[j] = __expf(v[j] - m); s += v[j]; }
#pragma unroll
    for (int off = 32; off; off >>= 1) s += __shfl_xor(s, off);
    if (lane == 0) redl[wave] = s;
    __syncthreads();
    s = redl[0] + redl[1] + redl[2] + redl[3];
    float inv = 1.0f / s;

#pragma unroll
    for (int j = 0; j < 8; j++) { a[j] = (f16)(v[j] * inv); b[j] = (f16)(v[8 + j] * inv); }
    *(f16x8*)(row + tid * 16) = a;
    *(f16x8*)(row + tid * 16 + 8) = b;
}

// ---------------------------------------------------------------------------
// softmax over one fp32 score row -> normalized fp16 (per-batch fallback)
// ---------------------------------------------------------------------------
__global__ __launch_bounds__(256) void softmax_row(
    const float* __restrict__ Sc, f16* __restrict__ P)
{
    const int q = blockIdx.x;
    const float* row = Sc + (size_t)q * S_;
    f16* prow = P + (size_t)q * S_;
    const int tid = threadIdx.x, wave = tid >> 6, lane = tid & 63;

    float4 v[4];
#pragma unroll
    for (int i = 0; i < 4; i++) v[i] = *(const float4*)(row + tid * 16 + i * 4);

    float m = -1e30f;
#pragma unroll
    for (int i = 0; i < 4; i++)
        m = fmaxf(m, fmaxf(fmaxf(v[i].x, v[i].y), fmaxf(v[i].z, v[i].w)));
#pragma unroll
    for (int off = 32; off; off >>= 1) m = fmaxf(m, __shfl_xor(m, off));
    __shared__ float redm[4], redl[4];
    if (lane == 0) redm[wave] = m;
    __syncthreads();
    m = fmaxf(fmaxf(redm[0], redm[1]), fmaxf(redm[2], redm[3]));

    float p[16];
    float s = 0.0f;
#pragma unroll
    for (int i = 0; i < 4; i++) {
        p[i * 4 + 0] = __expf(v[i].x - m);
        p[i * 4 + 1] = __expf(v[i].y - m);
        p[i * 4 + 2] = __expf(v[i].z - m);
        p[i * 4 + 3] = __expf(v[i].w - m);
        s += p[i * 4] + p[i * 4 + 1] + p[i * 4 + 2] + p[i * 4 + 3];
    }
#pragma unroll
    for (int off = 32; off; off >>= 1) s += __shfl_xor(s, off);
    if (lane == 0) redl[wave] = s;
    __syncthreads();
    s = redl[0] + redl[1] + redl[2] + redl[3];
    float inv = 1.0f / s;

    f16x8 o0, o1;
#pragma unroll
    for (int j = 0; j < 8; j++) {
        o0[j] = (f16)(p[j] * inv);
        o1[j] = (f16)(p[8 + j] * inv);
    }
    *(f16x8*)(prow + tid * 16) = o0;
    *(f16x8*)(prow + tid * 16 + 8) = o1;
}

// ---------------------------------------------------------------------------
// legacy fp32-input proj (flash fallback only)
// ---------------------------------------------------------------------------
#define SSTR 40
__global__ __launch_bounds__(256) void proj_gemm(
    const float* __restrict__ A, const float* __restrict__ W,
    const float* __restrict__ bias1, const float* __restrict__ bias2,
    bf16* __restrict__ C, float scale)
{
    __shared__ bf16 sA[64 * SSTR];
    __shared__ bf16 sB[64 * SSTR];
    const int tid = threadIdx.x;
    const int wave = tid >> 6, lane = tid & 63, quad = lane >> 4, l16 = lane & 15;
    const int m0 = blockIdx.x * 64, n0 = blockIdx.y * 64;
    const int wr = (wave >> 1) * 32, wc = (wave & 1) * 32;
    const int lr = tid >> 2;
    const int lc = (tid & 3) * 8;

    floatx4 acc[2][2];
#pragma unroll
    for (int i = 0; i < 2; i++)
#pragma unroll
        for (int j = 0; j < 2; j++) acc[i][j] = (floatx4)0.0f;

    for (int k0 = 0; k0 < 1024; k0 += 32) {
        const float* ga = A + (size_t)(m0 + lr) * 1024 + k0 + lc;
        const float* gw = W + (size_t)(n0 + lr) * 1024 + k0 + lc;
        float4 a0 = *(const float4*)ga;
        float4 a1 = *(const float4*)(ga + 4);
        float4 w0 = *(const float4*)gw;
        float4 w1 = *(const float4*)(gw + 4);
        *(bf16x8*)&sA[lr * SSTR + lc] = cvt8(a0, a1);
        *(bf16x8*)&sB[lr * SSTR + lc] = cvt8(w0, w1);
        __syncthreads();
        bf16x8 af[2], bfv[2];
        af[0]  = *(bf16x8*)&sA[(wr + l16) * SSTR + quad * 8];
        af[1]  = *(bf16x8*)&sA[(wr + 16 + l16) * SSTR + quad * 8];
        bfv[0] = *(bf16x8*)&sB[(wc + l16) * SSTR + quad * 8];
        bfv[1] = *(bf16x8*)&sB[(wc + 16 + l16) * SSTR + quad * 8];
#pragma unroll
        for (int mf = 0; mf < 2; mf++)
#pragma unroll
            for (int nf = 0; nf < 2; nf++)
                acc[mf][nf] = mfma16(af[mf], bfv[nf], acc[mf][nf]);
        __syncthreads();
    }
#pragma unroll
    for (int mf = 0; mf < 2; mf++)
#pragma unroll
        for (int nf = 0; nf < 2; nf++) {
            int col = n0 + wc + nf * 16 + l16;
            float bsum = bias1[col] + (bias2 ? bias2[col] : 0.0f);
#pragma unroll
            for (int r = 0; r < 4; r++) {
                int row = m0 + wr + mf * 16 + quad * 4 + r;
                C[(size_t)row * 1024 + col] = (bf16)((acc[mf][nf][r] + bsum) * scale);
            }
        }
}

// ---------------------------------------------------------------------------
// flash fallback (only if ws < 192MB)
// ---------------------------------------------------------------------------
#define BR 32
#define TK 64
#define DC 256
__global__ __launch_bounds__(256, 2) void flash_attn(
    const bf16* __restrict__ qb, const bf16* __restrict__ vb,
    const bf16* __restrict__ vtb, float* __restrict__ out)
{
    __shared__ float sPart[4][32][65];
    __shared__ bf16 sP[32][72];
    __shared__ float sM[32], sL[32], sAlpha[32];

    const int tid = threadIdx.x;
    const int wave = tid >> 6, lane = tid & 63, quad = lane >> 4, l16 = lane & 15;
    const int b = blockIdx.y, q0 = blockIdx.x * BR;

    bf16x8 qf[2][8];
#pragma unroll
    for (int mf = 0; mf < 2; mf++)
#pragma unroll
        for (int ks = 0; ks < 8; ks++) {
            int row = q0 + mf * 16 + l16;
            int col = wave * DC + ks * 32 + quad * 8;
            qf[mf][ks] = *(const bf16x8*)(qb + ((size_t)b * S_ + row) * D_ + col);
        }

    floatx4 o[2][16];
#pragma unroll
    for (int mf = 0; mf < 2; mf++)
#pragma unroll
        for (int nf = 0; nf < 16; nf++) o[mf][nf] = (floatx4)0.0f;

    if (tid < 32) { sM[tid] = -1e30f; sL[tid] = 0.0f; }
    __syncthreads();

    for (int kt = 0; kt < S_ / TK; kt++) {
        const int k0 = kt * TK;
        floatx4 sp[2][4];
#pragma unroll
        for (int mf = 0; mf < 2; mf++)
#pragma unroll
            for (int nf = 0; nf < 4; nf++) sp[mf][nf] = (floatx4)0.0f;
#pragma unroll
        for (int ks = 0; ks < 8; ks++) {
            int col = wave * DC + ks * 32 + quad * 8;
#pragma unroll
            for (int nf = 0; nf < 4; nf++) {
                int key = k0 + nf * 16 + l16;
                bf16x8 vf = *(const bf16x8*)(vb + ((size_t)b * S_ + key) * D_ + col);
                sp[0][nf] = mfma16(qf[0][ks], vf, sp[0][nf]);
                sp[1][nf] = mfma16(qf[1][ks], vf, sp[1][nf]);
            }
        }
#pragma unroll
        for (int mf = 0; mf < 2; mf++)
#pragma unroll
            for (int nf = 0; nf < 4; nf++)
#pragma unroll
                for (int r = 0; r < 4; r++)
                    sPart[wave][mf * 16 + quad * 4 + r][nf * 16 + l16] = sp[mf][nf][r];
        __syncthreads();

        {
            const int rr = tid >> 3, c0 = (tid & 7) * 8;
            float v[8];
            float mx = -1e30f;
#pragma unroll
            for (int j = 0; j < 8; j++) {
                v[j] = sPart[0][rr][c0 + j] + sPart[1][rr][c0 + j] +
                       sPart[2][rr][c0 + j] + sPart[3][rr][c0 + j];
                mx = fmaxf(mx, v[j]);
            }
            mx = fmaxf(mx, __shfl_xor(mx, 1));
            mx = fmaxf(mx, __shfl_xor(mx, 2));
            mx = fmaxf(mx, __shfl_xor(mx, 4));
            float m_old = sM[rr];
            float m_new = fmaxf(m_old, mx);
            float rsum = 0.0f;
#pragma unroll
            for (int j = 0; j < 8; j++) {
                float p = __expf(v[j] - m_new);
                sP[rr][c0 + j] = (bf16)p;
                rsum += p;
            }
            rsum += __shfl_xor(rsum, 1);
            rsum += __shfl_xor(rsum, 2);
            rsum += __shfl_xor(rsum, 4);
            if ((tid & 7) == 0) {
                float alpha = __expf(m_old - m_new);
                sAlpha[rr] = alpha;
                sM[rr] = m_new;
                sL[rr] = sL[rr] * alpha + rsum;
            }
        }
        __syncthreads();

        float al[2][4];
#pragma unroll
        for (int mf = 0; mf < 2; mf++)
#pragma unroll
            for (int r = 0; r < 4; r++) al[mf][r] = sAlpha[mf * 16 + quad * 4 + r];
#pragma unroll
        for (int mf = 0; mf < 2; mf++)
#pragma unroll
            for (int nf = 0; nf < 16; nf++)
#pragma unroll
                for (int r = 0; r < 4; r++) o[mf][nf][r] *= al[mf][r];

#pragma unroll
        for (int ks2 = 0; ks2 < 2; ks2++) {
            bf16x8 pA[2];
            pA[0] = *(bf16x8*)&sP[l16][ks2 * 32 + quad * 8];
            pA[1] = *(bf16x8*)&sP[16 + l16][ks2 * 32 + quad * 8];
            int key = k0 + ks2 * 32 + quad * 8;
#pragma unroll
            for (int nf = 0; nf < 16; nf++) {
                int d = wave * DC + nf * 16 + l16;
                bf16x8 vtf = *(const bf16x8*)(vtb + ((size_t)b * D_ + d) * S_ + key);
                o[0][nf] = mfma16(pA[0], vtf, o[0][nf]);
                o[1][nf] = mfma16(pA[1], vtf, o[1][nf]);
            }
        }
        __syncthreads();
    }

#pragma unroll
    for (int mf = 0; mf < 2; mf++) {
        float inv[4];
#pragma unroll
        for (int r = 0; r < 4; r++) inv[r] = 1.0f / sL[mf * 16 + quad * 4 + r];
#pragma unroll
        for (int nf = 0; nf < 16; nf++) {
            int d = wave * DC + nf * 16 + l16;
#pragma unroll
            for (int r = 0; r < 4; r++) {
                int row = q0 + mf * 16 + quad * 4 + r;
                out[((size_t)b * S_ + row) * D_ + d] = o[mf][nf][r] * inv[r];
            }
        }
    }
}

// ---------------------------------------------------------------------------
extern "C" void kernel_launch(void* const* d_in, const int* in_sizes, int n_in,
                              void* d_out, int out_size, void* d_ws, size_t ws_size,
                              hipStream_t stream) {
    const float* query = (const float*)d_in[0];
    const float* value = (const float*)d_in[1];
    const float* Wq    = (const float*)d_in[2];
    const float* bq    = (const float*)d_in[3];
    const float* qk_b  = (const float*)d_in[4];
    const float* Wv    = (const float*)d_in[5];
    const float* bv    = (const float*)d_in[6];
    float* out = (float*)d_out;

    const size_t SD = (size_t)S_ * D_;   // 4.19M elems
    const size_t SS = (size_t)S_ * S_;   // 16.8M elems
    const size_t MB = 1024 * 1024;

    char* w = (char*)d_ws;
    bf16* qb = (bf16*)w;                  // 32 MB (scale+bias folded)
    bf16* vb = (bf16*)(w + 32 * MB);      // 32 MB

    if (ws_size >= 224 * MB) {
        // ---- full batched path ----
        f16* vtb = (f16*)(w + 64 * MB);   // 32 MB [b][d][s]
        f16* Sc  = (f16*)(w + 96 * MB);   // 128 MB [b][q][k]; softmax in place
        // cast scratch aliases into the (not yet written) Sc region:
        bf16* qc  = (bf16*)(w + 96 * MB);   // 32 MB
        bf16* vc  = (bf16*)(w + 128 * MB);  // 32 MB
        bf16* wqc = (bf16*)(w + 160 * MB);  // 2 MB
        bf16* wvc = (bf16*)(w + 163 * MB);  // 2 MB

        cast_f32_bf16<<<(B_ * SD) / 2048, 256, 0, stream>>>(query, qc);
        cast_f32_bf16<<<(B_ * SD) / 2048, 256, 0, stream>>>(value, vc);
        cast_f32_bf16<<<((size_t)D_ * D_) / 2048, 256, 0, stream>>>(Wq, wqc);
        cast_f32_bf16<<<((size_t)D_ * D_) / 2048, 256, 0, stream>>>(Wv, wvc);

        // projections: [16384 x 1024] = [16384 x 1024] . [1024 x 1024]^T
        gemm128<bf16, bf16, true><<<dim3(128, 8, 1), 256, 0, stream>>>(
            qc, wqc, qb, D_, D_, 0, 0, 0, bq, qk_b, 0.125f);
        gemm128<bf16, bf16, true><<<dim3(128, 8, 1), 256, 0, stream>>>(
            vc, wvc, vb, D_, D_, 0, 0, 0, bv, nullptr, 1.0f);

        transpose_v_f16<<<dim3(S_ / 32, D_ / 32, B_), 256, 0, stream>>>(vb, vtb);

        // scores (all batches): Sc[b][q][k] = qb[b][q][:] . vb[b][k][:]
        gemm128<bf16, f16, false><<<dim3(32, 32, B_), 256, 0, stream>>>(
            qb, vb, Sc, D_, S_, SD, SD, SS, nullptr, nullptr, 1.0f);

        softmax_inplace_f16<<<B_ * S_, 256, 0, stream>>>(Sc);

        // O (all batches): out[b][q][d] = P[b][q][:] . vtb[b][d][:]
        gemm128<f16, float, false><<<dim3(32, 8, B_), 256, 0, stream>>>(
            Sc, vtb, out, S_, D_, SS, (size_t)D_ * S_, SD, nullptr, nullptr, 1.0f);
    } else if (ws_size >= 192 * MB) {
        // ---- per-batch fallback (fp32 scores) ----
        f16*   vtb = (f16*)(w + 64 * MB);     // 32 MB
        float* Sc  = (float*)(w + 96 * MB);   // 64 MB (one batch)
        f16*   Pn  = (f16*)(w + 160 * MB);    // 32 MB
        bf16*  qc  = (bf16*)(w + 96 * MB);    // cast scratch aliases Sc/Pn
        bf16*  vc  = (bf16*)(w + 128 * MB);
        bf16*  wqc = (bf16*)(w + 160 * MB);
        bf16*  wvc = (bf16*)(w + 163 * MB);

        cast_f32_bf16<<<(B_ * SD) / 2048, 256, 0, stream>>>(query, qc);
        cast_f32_bf16<<<(B_ * SD) / 2048, 256, 0, stream>>>(value, vc);
        cast_f32_bf16<<<((size_t)D_ * D_) / 2048, 256, 0, stream>>>(Wq, wqc);
        cast_f32_bf16<<<((size_t)D_ * D_) / 2048, 256, 0, stream>>>(Wv, wvc);

        gemm128<bf16, bf16, true><<<dim3(128, 8, 1), 256, 0, stream>>>(
            qc, wqc, qb, D_, D_, 0, 0, 0, bq, qk_b, 0.125f);
        gemm128<bf16, bf16, true><<<dim3(128, 8, 1), 256, 0, stream>>>(
            vc, wvc, vb, D_, D_, 0, 0, 0, bv, nullptr, 1.0f);

        transpose_v_f16<<<dim3(S_ / 32, D_ / 32, B_), 256, 0, stream>>>(vb, vtb);

        for (int b = 0; b < B_; b++) {
            gemm128<bf16, float, false><<<dim3(32, 32, 1), 256, 0, stream>>>(
                qb + b * SD, vb + b * SD, Sc, D_, S_, 0, 0, 0, nullptr, nullptr, 1.0f);
            softmax_row<<<S_, 256, 0, stream>>>(Sc, Pn);
            gemm128<f16, float, false><<<dim3(32, 8, 1), 256, 0, stream>>>(
                Pn, vtb + (size_t)b * D_ * S_, out + b * SD, S_, D_,
                0, 0, 0, nullptr, nullptr, 1.0f);
        }
    } else {
        // ---- flash fallback (96 MB) ----
        bf16* vtb = (bf16*)(w + 64 * MB);
        dim3 pg(16384 / 64, 1024 / 64);
        proj_gemm<<<pg, 256, 0, stream>>>(query, Wq, bq, qk_b, qb, 0.125f);
        proj_gemm<<<pg, 256, 0, stream>>>(value, Wv, bv, nullptr, vb, 1.0f);
        transpose_v<<<dim3(S_ / 32, D_ / 32, B_), 256, 0, stream>>>(vb, vtb);
        flash_attn<<<dim3(S_ / BR, B_), 256, 0, stream>>>(qb, vb, vtb, out);
    }
}